// Round 6
// baseline (613.425 us; speedup 1.0000x reference)
//
#include <hip/hip_runtime.h>

#define HEADS 4
#define EPS 1e-16f
#define SB 256    // scan blocks
#define EPB 1024  // edges per block (CSR build)

// bf16 helpers (RNE pack, cheap unpack via bit shifts)
__device__ inline unsigned short f2bf(float f) {
    union { float f; unsigned u; } v; v.f = f;
    unsigned r = v.u + 0x7FFFu + ((v.u >> 16) & 1u);
    return (unsigned short)(r >> 16);
}
#define BLO(u) __uint_as_float((u) << 16)
#define BHI(u) __uint_as_float((u) & 0xFFFF0000u)

// exact dst-range classifier: q = dst / qdiv, float approx + integer fix
__device__ inline int rangeOf(int dst, int qdiv, float inv) {
    int q = (int)((float)dst * inv);
    if (q > 7) q = 7;
    if ((long long)q * qdiv > dst) --q;
    else if ((long long)(q + 1) * qdiv <= dst) ++q;
    return q;
}

// ==== CSR pass 1: XCD-privatized degree histogram (deg8[bid&7][dst]) ======
__global__ __launch_bounds__(256) void hist8_kernel(
    const int* __restrict__ ei, int E, int n, int* __restrict__ deg8)
{
    int* slice = deg8 + (size_t)(blockIdx.x & 7) * n;
    int base = (blockIdx.x * 256 + threadIdx.x) * 4;
    if (base + 3 < E) {
        int4 d = *(const int4*)(ei + E + base);
        atomicAdd(slice + d.x, 1);
        atomicAdd(slice + d.y, 1);
        atomicAdd(slice + d.z, 1);
        atomicAdd(slice + d.w, 1);
    } else {
        for (int e = base; e < E; ++e)
            atomicAdd(slice + ei[E + e], 1);
    }
}

// ==== CSR pass 1b: deg[i] = sum_p deg8[p][i] ==============================
__global__ __launch_bounds__(256) void combine_kernel(
    const int* __restrict__ deg8, int* __restrict__ deg, int n)
{
    int i = blockIdx.x * 256 + threadIdx.x;
    if (i < n) {
        int s = 0;
        #pragma unroll
        for (int p = 0; p < 8; ++p) s += deg8[(size_t)p * n + i];
        deg[i] = s;
    }
}

// ============ CSR pass 2a: per-block partial sums of deg ==================
__global__ __launch_bounds__(256) void scan_partial(
    const int* __restrict__ deg, int* __restrict__ bsum, int n)
{
    __shared__ int red[256];
    int chunk = (n + SB - 1) / SB;
    int lo = blockIdx.x * chunk;
    int hi = min(lo + chunk, n);
    int s = 0;
    for (int i = lo + threadIdx.x; i < hi; i += 256) s += deg[i];
    red[threadIdx.x] = s;
    __syncthreads();
    for (int off = 128; off > 0; off >>= 1) {
        if (threadIdx.x < off) red[threadIdx.x] += red[threadIdx.x + off];
        __syncthreads();
    }
    if (threadIdx.x == 0) bsum[blockIdx.x] = red[0];
}

// ============ CSR pass 2b: exclusive scan of the 256 block sums ===========
__global__ __launch_bounds__(256) void scan_bsums(int* __restrict__ bsum)
{
    __shared__ int tmp[256];
    int t = threadIdx.x;
    tmp[t] = bsum[t];
    __syncthreads();
    for (int off = 1; off < 256; off <<= 1) {
        int add = (t >= off) ? tmp[t - off] : 0;
        __syncthreads();
        tmp[t] += add;
        __syncthreads();
    }
    bsum[t] = (t == 0) ? 0 : tmp[t - 1];
}

// ==== CSR pass 2c: per-block exclusive scan -> row_ptr (+ woff copy) ======
__global__ __launch_bounds__(256) void scan_write(
    const int* __restrict__ deg, const int* __restrict__ bsum,
    int* __restrict__ row_ptr, int* __restrict__ woff, int n)
{
    __shared__ int tmp[256];
    int chunk = (n + SB - 1) / SB;
    int lo = blockIdx.x * chunk;
    int hi = min(lo + chunk, n);
    int k = (chunk + 255) / 256;
    int tlo = lo + threadIdx.x * k;
    int thi = min(tlo + k, hi);
    int s = 0;
    for (int i = tlo; i < thi; ++i) s += deg[i];
    tmp[threadIdx.x] = s;
    __syncthreads();
    for (int off = 1; off < 256; off <<= 1) {
        int add = (threadIdx.x >= off) ? tmp[threadIdx.x - off] : 0;
        __syncthreads();
        tmp[threadIdx.x] += add;
        __syncthreads();
    }
    int prefix = bsum[blockIdx.x] + ((threadIdx.x == 0) ? 0 : tmp[threadIdx.x - 1]);
    for (int i = tlo; i < thi; ++i) {
        row_ptr[i] = prefix;
        woff[i] = prefix;
        prefix += deg[i];
    }
}

// ==== CSR pass 3a: bucket cursors = row_ptr at range starts ===============
__global__ void bucket_init(const int* __restrict__ row_ptr,
                            int* __restrict__ bcur, int n, int qdiv, int E)
{
    int q = threadIdx.x;
    if (q < 8) {
        int lo = q * qdiv;
        bcur[q] = (lo < n) ? row_ptr[lo] : E;
    }
}

// ==== CSR pass 3b: LDS-classified bucket scatter (coalesced flushes) ======
// Bucket q region = records[row_ptr[q*qdiv] .. row_ptr[(q+1)*qdiv]) exactly.
__global__ __launch_bounds__(256) void bucket_scatter(
    const int* __restrict__ ei, int E, int qdiv, float inv,
    int* __restrict__ bcur, int2* __restrict__ records)
{
    __shared__ int2 lrec[EPB];
    __shared__ int cnt[8], base[8], gbase[8];
    int b0 = blockIdx.x * EPB;
    int nloc = min(EPB, E - b0);
    if (threadIdx.x < 8) cnt[threadIdx.x] = 0;
    __syncthreads();
    int myq[4], myoff[4];
    int2 myrec[4];
    #pragma unroll
    for (int u = 0; u < 4; ++u) {
        int li = threadIdx.x + u * 256;
        if (li < nloc) {
            int e = b0 + li;
            int src = ei[e], dst = ei[E + e];
            int q = rangeOf(dst, qdiv, inv);
            myq[u] = q;
            myrec[u] = make_int2(src, dst);
            myoff[u] = atomicAdd(&cnt[q], 1);
        } else myq[u] = -1;
    }
    __syncthreads();
    if (threadIdx.x == 0) {
        int s = 0;
        #pragma unroll
        for (int q = 0; q < 8; ++q) { base[q] = s; s += cnt[q]; }
    }
    __syncthreads();
    #pragma unroll
    for (int u = 0; u < 4; ++u)
        if (myq[u] >= 0) lrec[base[myq[u]] + myoff[u]] = myrec[u];
    if (threadIdx.x < 8)
        gbase[threadIdx.x] = (cnt[threadIdx.x] > 0)
                           ? atomicAdd(&bcur[threadIdx.x], cnt[threadIdx.x]) : 0;
    __syncthreads();
    for (int q = 0; q < 8; ++q) {
        int c = cnt[q], gb = gbase[q], lb = base[q];
        for (int j = threadIdx.x; j < c; j += 256)
            records[gb + j] = lrec[lb + j];
    }
}

// ==== CSR pass 3c: per-range fill; woff atomics + col writes XCD-local ====
__global__ __launch_bounds__(256) void fill_bucket(
    const int2* __restrict__ records, const int* __restrict__ row_ptr,
    int* __restrict__ woff, int* __restrict__ col, int n, int qdiv, int E)
{
    int q = blockIdx.x & 7;
    int g = blockIdx.x >> 3, nb = gridDim.x >> 3;
    int lo = q * qdiv, hi = min(lo + qdiv, n);
    if (lo >= n) return;
    int rlo = row_ptr[lo];
    int rhi = (hi >= n) ? E : row_ptr[hi];
    for (int i = rlo + g * 256 + threadIdx.x; i < rhi; i += nb * 256) {
        int2 r = records[i];
        int pos = atomicAdd(&woff[r.y], 1);
        col[pos] = r.x;
    }
}

// ================= conv1: fused QKVS projection (128 -> 4x32) =============
// Outputs split: qs1[N][64] fp32 (q|s), kv1[N][64] bf16 (k|v, one 128B line)
__global__ __launch_bounds__(256) void proj1_kernel(
    const float* __restrict__ x,
    const float* __restrict__ Wq, const float* __restrict__ bq,
    const float* __restrict__ Wk, const float* __restrict__ bk,
    const float* __restrict__ Wv, const float* __restrict__ bv,
    const float* __restrict__ Ws, const float* __restrict__ bs,
    float* __restrict__ qs1, unsigned short* __restrict__ kv1, int n)
{
    __shared__ float Wl[128][128];
    __shared__ float xl[8][128];
    for (int i = threadIdx.x; i < 128 * 128; i += 256) {
        int k = i >> 7, c = i & 127;
        int sub = c >> 5, j = c & 31;
        const float* W = (sub == 0) ? Wq : (sub == 1) ? Wk : (sub == 2) ? Wv : Ws;
        Wl[k][c] = W[k * 32 + j];
    }
    int col4 = (threadIdx.x & 31) * 4;
    int sub = col4 >> 5, j = col4 & 31;
    float4 bias4;
    {
        const float* b = (sub == 0) ? bq : (sub == 1) ? bk : (sub == 2) ? bv : bs;
        bias4 = *(const float4*)(b + j);
    }
    __syncthreads();
    int row_in = threadIdx.x >> 5;   // 0..7
    for (int row0 = blockIdx.x * 8; row0 < n; row0 += gridDim.x * 8) {
        int f4 = threadIdx.x;
        int gr = row0 + (f4 >> 5);
        float4 xv = (gr < n) ? *(const float4*)(x + (size_t)gr * 128 + (f4 & 31) * 4)
                             : make_float4(0.f, 0.f, 0.f, 0.f);
        *(float4*)(&xl[f4 >> 5][(f4 & 31) * 4]) = xv;
        __syncthreads();
        float4 acc = bias4;
        #pragma unroll 8
        for (int k = 0; k < 128; ++k) {
            float xr = xl[row_in][k];
            float4 w = *(const float4*)(&Wl[k][col4]);
            acc.x += xr * w.x; acc.y += xr * w.y;
            acc.z += xr * w.z; acc.w += xr * w.w;
        }
        int row = row0 + row_in;
        if (row < n) {
            if (sub == 0)
                *(float4*)(qs1 + (size_t)row * 64 + j) = acc;
            else if (sub == 3)
                *(float4*)(qs1 + (size_t)row * 64 + 32 + j) = acc;
            else {
                ushort4 p = make_ushort4(f2bf(acc.x), f2bf(acc.y), f2bf(acc.z), f2bf(acc.w));
                *(ushort4*)(kv1 + (size_t)row * 64 + ((sub == 1) ? 0 : 32) + j) = p;
            }
        }
        __syncthreads();
    }
}

// ================= conv2 projection (32 -> 4x16) ==========================
// Outputs split: qs2[N][32] fp32 (q|s), kv2[N][32] bf16 (k|v, 64B)
__global__ __launch_bounds__(256) void proj2_kernel(
    const float* __restrict__ h1,
    const float* __restrict__ Wq, const float* __restrict__ bq,
    const float* __restrict__ Wk, const float* __restrict__ bk,
    const float* __restrict__ Wv, const float* __restrict__ bv,
    const float* __restrict__ Ws, const float* __restrict__ bs,
    float* __restrict__ qs2, unsigned short* __restrict__ kv2, int n)
{
    __shared__ float Wl[32][64];
    __shared__ float bl[64];
    __shared__ float xl[4][32];
    for (int i = threadIdx.x; i < 32 * 64; i += 256) {
        int k = i >> 6, c = i & 63;
        int sub = c >> 4, j = c & 15;
        const float* W = (sub == 0) ? Wq : (sub == 1) ? Wk : (sub == 2) ? Wv : Ws;
        Wl[k][c] = W[k * 16 + j];
    }
    if (threadIdx.x < 64) {
        int c = threadIdx.x, sub = c >> 4, j = c & 15;
        const float* b = (sub == 0) ? bq : (sub == 1) ? bk : (sub == 2) ? bv : bs;
        bl[c] = b[j];
    }
    __syncthreads();
    int r = threadIdx.x >> 6, col = threadIdx.x & 63;
    int sub = col >> 4, j = col & 15;
    for (int row0 = blockIdx.x * 4; row0 < n; row0 += gridDim.x * 4) {
        int li = threadIdx.x;
        if (li < 128) {
            int rr = row0 + (li >> 5);
            if (rr < n) xl[li >> 5][li & 31] = h1[(size_t)rr * 32 + (li & 31)];
        }
        __syncthreads();
        int row = row0 + r;
        if (row < n) {
            float acc = bl[col];
            #pragma unroll
            for (int k = 0; k < 32; ++k) acc += xl[r][k] * Wl[k][col];
            if (sub == 0)       qs2[(size_t)row * 32 + j] = acc;
            else if (sub == 3)  qs2[(size_t)row * 32 + 16 + j] = acc;
            else                kv2[(size_t)row * 32 + ((sub == 1) ? 0 : 16) + j] = f2bf(acc);
        }
        __syncthreads();
    }
}

// ===== conv1 fused gather: online softmax, bf16 KV, 1-deep SW pipeline ====
__global__ __launch_bounds__(256) void gather_conv1(
    const int* __restrict__ row_ptr, const int* __restrict__ deg,
    const int* __restrict__ col, const float* __restrict__ qs1,
    const unsigned short* __restrict__ kv1, float* __restrict__ h1, int n)
{
    int tid = blockIdx.x * 256 + threadIdx.x;
    if (tid >= n * HEADS) return;
    int node = tid >> 2, h = tid & 3;
    const float4* qp = (const float4*)(qs1 + (size_t)node * 64 + h * 8);
    float4 q0 = qp[0], q1 = qp[1];
    int start = row_ptr[node], d = deg[node];
    float m = -INFINITY, s = 0.f;
    float a0x=0,a0y=0,a0z=0,a0w=0,a1x=0,a1y=0,a1z=0,a1w=0;
    uint4 ku = make_uint4(0,0,0,0), vu = make_uint4(0,0,0,0);
    if (d > 0) {
        const unsigned short* b0 = kv1 + (size_t)col[start] * 64;
        ku = *(const uint4*)(b0 + h * 8);
        vu = *(const uint4*)(b0 + 32 + h * 8);
    }
    for (int i = 0; i < d; ++i) {
        uint4 kn = ku, vn = vu;
        if (i + 1 < d) {
            const unsigned short* nb = kv1 + (size_t)col[start + i + 1] * 64;
            kn = *(const uint4*)(nb + h * 8);
            vn = *(const uint4*)(nb + 32 + h * 8);
        }
        float a = (q0.x*BLO(ku.x) + q0.y*BHI(ku.x)
                 + q0.z*BLO(ku.y) + q0.w*BHI(ku.y)
                 + q1.x*BLO(ku.z) + q1.y*BHI(ku.z)
                 + q1.z*BLO(ku.w) + q1.w*BHI(ku.w))
                * 0.35355339059327373f;  // 1/sqrt(8)
        float mn = fmaxf(m, a);
        float corr = __expf(m - mn);   // first iter: exp(-inf)=0
        float ea = __expf(a - mn);
        s = s * corr + ea;
        a0x = a0x*corr + ea*BLO(vu.x); a0y = a0y*corr + ea*BHI(vu.x);
        a0z = a0z*corr + ea*BLO(vu.y); a0w = a0w*corr + ea*BHI(vu.y);
        a1x = a1x*corr + ea*BLO(vu.z); a1y = a1y*corr + ea*BHI(vu.z);
        a1z = a1z*corr + ea*BLO(vu.w); a1w = a1w*corr + ea*BHI(vu.w);
        m = mn;
        ku = kn; vu = vn;
    }
    float inv = 1.f / (s + EPS);
    const float* sk = qs1 + (size_t)node * 64 + 32 + h * 8;
    float4 o0, o1;
    o0.x = fmaxf(a0x*inv + sk[0], 0.f); o0.y = fmaxf(a0y*inv + sk[1], 0.f);
    o0.z = fmaxf(a0z*inv + sk[2], 0.f); o0.w = fmaxf(a0w*inv + sk[3], 0.f);
    o1.x = fmaxf(a1x*inv + sk[4], 0.f); o1.y = fmaxf(a1y*inv + sk[5], 0.f);
    o1.z = fmaxf(a1z*inv + sk[6], 0.f); o1.w = fmaxf(a1w*inv + sk[7], 0.f);
    float4* op = (float4*)(h1 + (size_t)node * 32 + h * 8);
    op[0] = o0; op[1] = o1;
}

// ===== conv2 fused gather (C=4), bf16 KV, 1-deep SW pipeline ==============
__global__ __launch_bounds__(256) void gather_conv2(
    const int* __restrict__ row_ptr, const int* __restrict__ deg,
    const int* __restrict__ col, const float* __restrict__ qs2,
    const unsigned short* __restrict__ kv2, float* __restrict__ h2, int n)
{
    int tid = blockIdx.x * 256 + threadIdx.x;
    if (tid >= n * HEADS) return;
    int node = tid >> 2, h = tid & 3;
    float4 q = *(const float4*)(qs2 + (size_t)node * 32 + h * 4);
    int start = row_ptr[node], d = deg[node];
    float m = -INFINITY, s = 0.f;
    float ax=0, ay=0, az=0, aw=0;
    uint2 ku = make_uint2(0,0), vu = make_uint2(0,0);
    if (d > 0) {
        const unsigned short* b0 = kv2 + (size_t)col[start] * 32;
        ku = *(const uint2*)(b0 + h * 4);
        vu = *(const uint2*)(b0 + 16 + h * 4);
    }
    for (int i = 0; i < d; ++i) {
        uint2 kn = ku, vn = vu;
        if (i + 1 < d) {
            const unsigned short* nb = kv2 + (size_t)col[start + i + 1] * 32;
            kn = *(const uint2*)(nb + h * 4);
            vn = *(const uint2*)(nb + 16 + h * 4);
        }
        float a = (q.x*BLO(ku.x) + q.y*BHI(ku.x)
                 + q.z*BLO(ku.y) + q.w*BHI(ku.y)) * 0.5f; // 1/sqrt(4)
        float mn = fmaxf(m, a);
        float corr = __expf(m - mn);
        float ea = __expf(a - mn);
        s = s * corr + ea;
        ax = ax*corr + ea*BLO(vu.x); ay = ay*corr + ea*BHI(vu.x);
        az = az*corr + ea*BLO(vu.y); aw = aw*corr + ea*BHI(vu.y);
        m = mn;
        ku = kn; vu = vn;
    }
    float inv = 1.f / (s + EPS);
    const float* sk = qs2 + (size_t)node * 32 + 16 + h * 4;
    float4 o;
    o.x = fmaxf(ax*inv + sk[0], 0.f);
    o.y = fmaxf(ay*inv + sk[1], 0.f);
    o.z = fmaxf(az*inv + sk[2], 0.f);
    o.w = fmaxf(aw*inv + sk[3], 0.f);
    *(float4*)(h2 + (size_t)node * 16 + h * 4) = o;
}

// ====== mean-pool accumulation over h2 (block-local reduce, batch sorted) =
__global__ __launch_bounds__(256) void pool_kernel(
    const float* __restrict__ h2, const int* __restrict__ batch,
    float* __restrict__ pooled, float* __restrict__ cnt, int n)
{
    __shared__ float acc[16];
    __shared__ int bShared;
    __shared__ int uniform;
    int node0 = blockIdx.x * 16;
    int t = threadIdx.x;
    int node = node0 + (t >> 4), j = t & 15;
    if (t == 0) {
        int bFirst = batch[node0];
        int bLast = batch[min(node0 + 15, n - 1)];
        bShared = bFirst;
        uniform = (bFirst == bLast);
    }
    if (t < 16) acc[t] = 0.f;
    __syncthreads();
    bool active = node < n;
    float val = active ? h2[(size_t)node * 16 + j] : 0.f;
    if (uniform) {
        if (active) atomicAdd(&acc[j], val);
        __syncthreads();
        int nlocal = min(16, n - node0);
        if (t < 16) atomicAdd(pooled + bShared * 16 + t, acc[t]);
        if (t == 0) atomicAdd(cnt + bShared, (float)nlocal);
    } else {
        if (active) {
            int b = batch[node];
            atomicAdd(pooled + b * 16 + j, val);
            if (j == 0) atomicAdd(cnt + b, 1.f);
        }
    }
}

// ================= final FC on pooled [64,16] -> [64,10] ==================
__global__ void fc_kernel(
    const float* __restrict__ pooled, const float* __restrict__ cnt,
    const float* __restrict__ Wfc, const float* __restrict__ bfc,
    float* __restrict__ out)
{
    int t = threadIdx.x;
    if (t < 64 * 10) {
        int b = t / 10, o = t % 10;
        float c = fmaxf(cnt[b], 1.0f);
        float acc = bfc[o];
        #pragma unroll
        for (int k = 0; k < 16; ++k)
            acc += (pooled[b * 16 + k] / c) * Wfc[k * 10 + o];
        out[t] = acc;
    }
}

extern "C" void kernel_launch(void* const* d_in, const int* in_sizes, int n_in,
                              void* d_out, int out_size, void* d_ws, size_t ws_size,
                              hipStream_t stream) {
    const float* x     = (const float*)d_in[0];
    const int*   ei    = (const int*)d_in[1];
    const int*   batch = (const int*)d_in[2];
    const float* Wq1 = (const float*)d_in[3],  *bq1 = (const float*)d_in[4];
    const float* Wk1 = (const float*)d_in[5],  *bk1 = (const float*)d_in[6];
    const float* Wv1 = (const float*)d_in[7],  *bv1 = (const float*)d_in[8];
    const float* Ws1 = (const float*)d_in[9],  *bs1 = (const float*)d_in[10];
    const float* Wq2 = (const float*)d_in[11], *bq2 = (const float*)d_in[12];
    const float* Wk2 = (const float*)d_in[13], *bk2 = (const float*)d_in[14];
    const float* Wv2 = (const float*)d_in[15], *bv2 = (const float*)d_in[16];
    const float* Ws2 = (const float*)d_in[17], *bs2 = (const float*)d_in[18];
    const float* Wfc = (const float*)d_in[19], *bfc = (const float*)d_in[20];

    int N = in_sizes[0] / 128;
    int E = in_sizes[1] / 2;
    int qdiv = (N + 7) / 8;
    float qinv = 1.0f / (float)qdiv;

    // ---- workspace layout ----
    float* ws = (float*)d_ws;
    float* qs1    = ws;                                   // N*64 f  (q|s conv1)
    float* h1     = qs1 + (size_t)N * 64;                 // N*32 f
    float* h2     = h1 + (size_t)N * 32;                  // N*16 f
    float* qs2    = h2 + (size_t)N * 16;                  // N*32 f  (q|s conv2)
    float* pooled = qs2 + (size_t)N * 32;                 // 1024 f
    float* cnt    = pooled + 1024;                        // 64 f
    unsigned short* kv1 = (unsigned short*)(cnt + 64);    // N*64 bf16 (128B/node)
    unsigned short* kv2 = kv1 + (size_t)N * 64;           // N*32 bf16 (64B/node)
    int* deg8    = (int*)(kv2 + (size_t)N * 32);          // 8*N ints (privatized hist)
    int* deg     = deg8 + (size_t)8 * N;                  // N ints
    int* row_ptr = deg + N;                               // N ints
    int* woff    = row_ptr + N;                           // N ints
    int* bsum    = woff + N;                              // SB ints
    int* bcur    = bsum + SB;                             // 8 ints
    int* col     = bcur + 8;                              // E ints
    // records (E int2 = 25.6MB) aliases h1+h2+qs2 (32MB), all written later
    int2* records = (int2*)h1;

    // zero: deg8 (histogram) + pooled + cnt. every call (no re-poison).
    hipMemsetAsync(deg8, 0, (size_t)8 * N * sizeof(int), stream);
    hipMemsetAsync(pooled, 0, (64 * 16 + 64) * sizeof(float), stream);

    int ngrid = (N * HEADS + 255) / 256;
    int ebgrid = (E + EPB - 1) / EPB;

    // ---- CSR build (counting-sort, XCD-local atomics) ----
    hist8_kernel<<<ebgrid, 256, 0, stream>>>(ei, E, N, deg8);
    combine_kernel<<<(N + 255) / 256, 256, 0, stream>>>(deg8, deg, N);
    scan_partial<<<SB, 256, 0, stream>>>(deg, bsum, N);
    scan_bsums<<<1, 256, 0, stream>>>(bsum);
    scan_write<<<SB, 256, 0, stream>>>(deg, bsum, row_ptr, woff, N);
    bucket_init<<<1, 8, 0, stream>>>(row_ptr, bcur, N, qdiv, E);
    bucket_scatter<<<ebgrid, 256, 0, stream>>>(ei, E, qdiv, qinv, bcur, records);
    fill_bucket<<<2048, 256, 0, stream>>>(records, row_ptr, woff, col, N, qdiv, E);

    // ---- conv1 ----
    proj1_kernel<<<1024, 256, 0, stream>>>(x, Wq1, bq1, Wk1, bk1, Wv1, bv1, Ws1, bs1, qs1, kv1, N);
    gather_conv1<<<ngrid, 256, 0, stream>>>(row_ptr, deg, col, qs1, kv1, h1, N);

    // ---- conv2 ----
    proj2_kernel<<<1024, 256, 0, stream>>>(h1, Wq2, bq2, Wk2, bk2, Wv2, bv2, Ws2, bs2, qs2, kv2, N);
    gather_conv2<<<ngrid, 256, 0, stream>>>(row_ptr, deg, col, qs2, kv2, h2, N);

    // ---- pool + fc ----
    pool_kernel<<<(N + 15) / 16, 256, 0, stream>>>(h2, batch, pooled, cnt, N);
    fc_kernel<<<1, 640, 0, stream>>>(pooled, cnt, Wfc, bfc, (float*)d_out);
}